// Round 1
// baseline (4915.517 us; speedup 1.0000x reference)
//
#include <hip/hip_runtime.h>
#include <hip/hip_bf16.h>
#include <math.h>

#define B_ 64
#define T_ 60
#define S_ 60
#define H_ 512
#define V_ 32000
#define L_ 2
#define BT_ (B_*T_)

typedef __attribute__((ext_vector_type(8))) short short8;
typedef __attribute__((ext_vector_type(4))) float f32x4;

__device__ __forceinline__ short f2bf(float x) {
  __hip_bfloat16 h = __float2bfloat16(x);
  return __builtin_bit_cast(short, h);
}

// ---------------- embedding gather (f32 -> bf16) ----------------
__global__ __launch_bounds__(256) void embed_k(const int* __restrict__ idx,
                                               const float* __restrict__ emb,
                                               __hip_bfloat16* __restrict__ xb) {
  int e = blockIdx.x * 256 + threadIdx.x;   // exact: BT_*H_ elements
  int bt = e >> 9, h = e & (H_ - 1);
  int row = idx[bt];
  xb[e] = __float2bfloat16(emb[(size_t)row * H_ + h]);
}

// ---------------- generic C = A(bf16) @ B(f32->bf16)^T + bias ----------------
// A: [M,K] bf16 row-major, Bw: [N,K] f32 row-major. M,N multiples of 128, K of 32.
#define LDSROW 40   // bf16 elems per LDS row (80B: 16B-aligned, conflict-light)

template<bool OUT_BF16>
__global__ __launch_bounds__(256) void gemm_bt_k(
    const __hip_bfloat16* __restrict__ A, const float* __restrict__ Bw,
    const float* __restrict__ bias, float* __restrict__ Cf,
    __hip_bfloat16* __restrict__ Cb, int M, int N, int K) {
  __shared__ short As[128 * LDSROW];
  __shared__ short Bs[128 * LDSROW];
  int tid = threadIdx.x;
  int bm = blockIdx.y * 128, bn = blockIdx.x * 128;
  int wid = tid >> 6, lane = tid & 63;
  int wr = wid >> 1, wc = wid & 1;
  int lrow = lane & 15, lk = (lane >> 4) * 8;
  f32x4 acc[4][4];
#pragma unroll
  for (int i = 0; i < 4; ++i)
#pragma unroll
    for (int j = 0; j < 4; ++j) acc[i][j] = (f32x4){0.f, 0.f, 0.f, 0.f};

  int srow = tid >> 2, scol = (tid & 3) * 8;
  const short* Ash = (const short*)A;

  for (int k0 = 0; k0 < K; k0 += 32) {
#pragma unroll
    for (int it = 0; it < 2; ++it) {
      int r = srow + it * 64;
      short8 av = *(const short8*)(Ash + (size_t)(bm + r) * K + k0 + scol);
      *(short8*)(As + r * LDSROW + scol) = av;
      const float* bp = Bw + (size_t)(bn + r) * K + k0 + scol;
      float4 b0 = *(const float4*)(bp);
      float4 b1 = *(const float4*)(bp + 4);
      short8 bv;
      bv[0] = f2bf(b0.x); bv[1] = f2bf(b0.y); bv[2] = f2bf(b0.z); bv[3] = f2bf(b0.w);
      bv[4] = f2bf(b1.x); bv[5] = f2bf(b1.y); bv[6] = f2bf(b1.z); bv[7] = f2bf(b1.w);
      *(short8*)(Bs + r * LDSROW + scol) = bv;
    }
    __syncthreads();
    short8 af[4], bfr[4];
#pragma unroll
    for (int i = 0; i < 4; ++i)
      af[i] = *(const short8*)(As + (wr * 64 + i * 16 + lrow) * LDSROW + lk);
#pragma unroll
    for (int j = 0; j < 4; ++j)
      bfr[j] = *(const short8*)(Bs + (wc * 64 + j * 16 + lrow) * LDSROW + lk);
#pragma unroll
    for (int i = 0; i < 4; ++i)
#pragma unroll
      for (int j = 0; j < 4; ++j)
        acc[i][j] = __builtin_amdgcn_mfma_f32_16x16x32_bf16(af[i], bfr[j], acc[i][j], 0, 0, 0);
    __syncthreads();
  }

#pragma unroll
  for (int j = 0; j < 4; ++j) {
    int col = bn + wc * 64 + j * 16 + lrow;
    float bv = bias[col];
#pragma unroll
    for (int i = 0; i < 4; ++i) {
#pragma unroll
      for (int r = 0; r < 4; ++r) {
        int row = bm + wr * 64 + i * 16 + (lane >> 4) * 4 + r;
        float v = acc[i][j][r] + bv;
        if (OUT_BF16) Cb[(size_t)row * N + col] = __float2bfloat16(v);
        else          Cf[(size_t)row * N + col] = v;
      }
    }
  }
}

// ---------------- one LSTM time step (fp32) ----------------
// grid = H_/JB blocks; block owns JB hidden j's (all 4 gates, all 64 batches).
// h(t-1) is read from dec[:, t-1, :]; h(t) written to dec[:, t, :]; c in place.
#define JB 4
__global__ __launch_bounds__(256) void lstm_step_k(
    const float* __restrict__ xg, const float* __restrict__ whh,
    const float* __restrict__ bhh, float* __restrict__ dec,
    float* __restrict__ c, int t) {
  int tid = threadIdx.x;
  int nIdx = tid & 15;          // gate*4 + joff
  int bGrp = tid >> 4;          // 16 groups x 4 batches
  int gate = nIdx >> 2, joff = nIdx & 3;
  int jglob = blockIdx.x * JB + joff;
  int nglob = gate * H_ + jglob;
  const float* wrow = whh + (size_t)nglob * H_;
  float acc[4] = {0.f, 0.f, 0.f, 0.f};
  if (t > 0) {
    const float* hbase = dec + (size_t)(t - 1) * H_;
    for (int k = 0; k < H_; k += 4) {
      float4 wv = *(const float4*)(wrow + k);
#pragma unroll
      for (int i = 0; i < 4; ++i) {
        int b = bGrp * 4 + i;
        float4 hv = *(const float4*)(hbase + (size_t)b * (T_ * H_) + k);
        acc[i] += wv.x * hv.x + wv.y * hv.y + wv.z * hv.z + wv.w * hv.w;
      }
    }
  }
  __shared__ float g_lds[16][65];
  float bb = bhh[nglob];
#pragma unroll
  for (int i = 0; i < 4; ++i) {
    int b = bGrp * 4 + i;
    float g = acc[i] + xg[((size_t)b * T_ + t) * (4 * H_) + nglob] + bb;
    g_lds[nIdx][b] = g;
  }
  __syncthreads();
  int b2 = tid >> 2, j2 = tid & 3;
  int jg = blockIdx.x * JB + j2;
  float gi = g_lds[0 * 4 + j2][b2];
  float gf = g_lds[1 * 4 + j2][b2];
  float gg = g_lds[2 * 4 + j2][b2];
  float go = g_lds[3 * 4 + j2][b2];
  float cv = c[(size_t)b2 * H_ + jg];
  float i_ = 1.f / (1.f + expf(-gi));
  float f_ = 1.f / (1.f + expf(-gf));
  float o_ = 1.f / (1.f + expf(-go));
  float cn = f_ * cv + i_ * tanhf(gg);
  float hn = o_ * tanhf(cn);
  c[(size_t)b2 * H_ + jg] = cn;
  dec[((size_t)b2 * T_ + t) * H_ + jg] = hn;
}

// ---------------- attention + softmax + concat (fp32 compute, bf16 out) -------
__global__ __launch_bounds__(256) void attn_k(const float* __restrict__ dec,
                                              const float* __restrict__ enc,
                                              const int* __restrict__ lens,
                                              __hip_bfloat16* __restrict__ cat) {
  int bt = blockIdx.x;
  int b = bt / T_;
  __shared__ float dsh[H_];
  __shared__ float p[64];
  int tid = threadIdx.x;
  dsh[tid] = dec[(size_t)bt * H_ + tid];
  dsh[tid + 256] = dec[(size_t)bt * H_ + tid + 256];
  __syncthreads();
  int wid = tid >> 6, lane = tid & 63;
  int len = lens[b];
  for (int s = wid; s < S_; s += 4) {
    const float* er = enc + ((size_t)(b * S_ + s)) * H_ + lane * 8;
    float4 e0 = *(const float4*)(er);
    float4 e1 = *(const float4*)(er + 4);
    const float* dr = dsh + lane * 8;
    float sum = e0.x * dr[0] + e0.y * dr[1] + e0.z * dr[2] + e0.w * dr[3]
              + e1.x * dr[4] + e1.y * dr[5] + e1.z * dr[6] + e1.w * dr[7];
#pragma unroll
    for (int off = 32; off > 0; off >>= 1) sum += __shfl_down(sum, off);
    if (lane == 0) p[s] = sum + (s < len ? 0.f : -1.0e9f);
  }
  __syncthreads();
  if (wid == 0) {
    float v = (lane < S_) ? p[lane] : -INFINITY;
    float m = v;
#pragma unroll
    for (int off = 32; off > 0; off >>= 1) m = fmaxf(m, __shfl_down(m, off));
    m = __shfl(m, 0);
    float e = (lane < S_) ? expf(v - m) : 0.f;
    float ssum = e;
#pragma unroll
    for (int off = 32; off > 0; off >>= 1) ssum += __shfl_down(ssum, off);
    ssum = __shfl(ssum, 0);
    if (lane < S_) p[lane] = e / ssum;
  }
  __syncthreads();
  int h = tid * 2;
  float a0 = 0.f, a1 = 0.f;
  for (int s = 0; s < S_; ++s) {
    float ps = p[s];
    const float* er = enc + ((size_t)(b * S_ + s)) * H_ + h;
    a0 += ps * er[0];
    a1 += ps * er[1];
  }
  size_t base = (size_t)bt * (2 * H_);
  cat[base + h]          = __float2bfloat16(dsh[h]);
  cat[base + h + 1]      = __float2bfloat16(dsh[h + 1]);
  cat[base + H_ + h]     = __float2bfloat16(a0);
  cat[base + H_ + h + 1] = __float2bfloat16(a1);
}

extern "C" void kernel_launch(void* const* d_in, const int* in_sizes, int n_in,
                              void* d_out, int out_size, void* d_ws, size_t ws_size,
                              hipStream_t stream) {
  (void)in_sizes; (void)n_in; (void)out_size; (void)ws_size;
  const int*   indices = (const int*)d_in[0];
  const float* enc     = (const float*)d_in[1];
  const int*   de_lens = (const int*)d_in[2];
  const float* emb     = (const float*)d_in[3];
  const float* w_ih    = (const float*)d_in[4];   // [2,2048,512]
  const float* w_hh    = (const float*)d_in[5];   // [2,2048,512]
  const float* b_ih    = (const float*)d_in[6];   // [2,2048]
  const float* b_hh    = (const float*)d_in[7];   // [2,2048]
  const float* lin_w   = (const float*)d_in[8];   // [2,512,1024]
  const float* lin_b   = (const float*)d_in[9];   // [2,512]
  const float* out_w   = (const float*)d_in[10];  // [32000,512]
  const float* out_b   = (const float*)d_in[11];  // [32000]
  float* outp = (float*)d_out;

  char* ws = (char*)d_ws;
  size_t off = 0;
  auto alloc = [&](size_t bytes) -> void* {
    void* p = ws + off; off += (bytes + 255) & ~(size_t)255; return p;
  };
  __hip_bfloat16* x_bf = (__hip_bfloat16*)alloc((size_t)BT_ * H_ * 2);      // layer input
  float* xg            = (float*)alloc((size_t)BT_ * 4 * H_ * 4);           // [B,T,4H]
  float* dec           = (float*)alloc((size_t)BT_ * H_ * 4);               // [B,T,H]
  float* cbuf          = (float*)alloc((size_t)B_ * H_ * 4);                // [B,H]
  __hip_bfloat16* cat  = (__hip_bfloat16*)alloc((size_t)BT_ * 2 * H_ * 2);  // [B,T,2H]

  embed_k<<<BT_ * H_ / 256, 256, 0, stream>>>(indices, emb, x_bf);

  for (int l = 0; l < L_; ++l) {
    // xg = x @ w_ih^T + b_ih     [3840,2048]
    gemm_bt_k<false><<<dim3(4 * H_ / 128, BT_ / 128), 256, 0, stream>>>(
        x_bf, w_ih + (size_t)l * 4 * H_ * H_, b_ih + l * 4 * H_,
        xg, nullptr, BT_, 4 * H_, H_);
    hipMemsetAsync(cbuf, 0, (size_t)B_ * H_ * 4, stream);
    for (int t = 0; t < T_; ++t)
      lstm_step_k<<<H_ / JB, 256, 0, stream>>>(
          xg, w_hh + (size_t)l * 4 * H_ * H_, b_hh + l * 4 * H_, dec, cbuf, t);
    attn_k<<<BT_, 256, 0, stream>>>(dec, enc, de_lens, cat);
    // x = cat @ lin_w^T + lin_b  -> bf16 [3840,512]
    gemm_bt_k<true><<<dim3(H_ / 128, BT_ / 128), 256, 0, stream>>>(
        cat, lin_w + (size_t)l * H_ * 2 * H_, lin_b + l * H_,
        nullptr, x_bf, BT_, H_, 2 * H_);
  }

  // out = x @ out_w^T + out_b   [3840,32000]
  gemm_bt_k<false><<<dim3(V_ / 128, BT_ / 128), 256, 0, stream>>>(
      x_bf, out_w, out_b, outp, nullptr, BT_, V_, H_);
}